// Round 2
// baseline (665.688 us; speedup 1.0000x reference)
//
#include <hip/hip_runtime.h>

static constexpr int NN  = 100000;   // nodes
static constexpr int NE  = 1200000;  // edges
static constexpr int KIN = 256;      // input dim
static constexpr int HID = 64;       // hidden == output dim

// ---------- zero helper (avoid hipMemsetAsync during graph capture)
__global__ void k_zero(int* __restrict__ p, int n) {
  int i = blockIdx.x * 256 + threadIdx.x;
  if (i < n) p[i] = 0;
}

// ---------- degree histogram (in-degree from edges only; +1 self-loop added later)
__global__ void k_deg(const int* __restrict__ ed, int* __restrict__ edeg) {
  int e = blockIdx.x * 256 + threadIdx.x;
  if (e < NE) atomicAdd(&edeg[ed[NE + e]], 1);
}

__global__ void k_dinv(const int* __restrict__ edeg, float* __restrict__ dinv) {
  int i = blockIdx.x * 256 + threadIdx.x;
  if (i < NN) dinv[i] = rsqrtf((float)(edeg[i] + 1));
}

// ---------- exclusive scan of edeg -> row_ptr (3-kernel: block-local, block sums, add)
__global__ void k_scan1(const int* __restrict__ deg, int* __restrict__ rp, int* __restrict__ bsum) {
  __shared__ int sh[256];
  int t = threadIdx.x;
  int base = blockIdx.x * 1024 + t * 4;
  int v0 = 0, v1 = 0, v2 = 0, v3 = 0;
  if (base + 0 < NN) v0 = deg[base + 0];
  if (base + 1 < NN) v1 = deg[base + 1];
  if (base + 2 < NN) v2 = deg[base + 2];
  if (base + 3 < NN) v3 = deg[base + 3];
  int s = v0 + v1 + v2 + v3;
  sh[t] = s;
  __syncthreads();
  #pragma unroll
  for (int off = 1; off < 256; off <<= 1) {
    int x = (t >= off) ? sh[t - off] : 0;
    __syncthreads();
    sh[t] += x;
    __syncthreads();
  }
  int pre = sh[t] - s;  // exclusive prefix of this thread's chunk
  if (t == 255) bsum[blockIdx.x] = sh[255];
  if (base + 0 < NN) rp[base + 0] = pre;
  pre += v0;
  if (base + 1 < NN) rp[base + 1] = pre;
  pre += v1;
  if (base + 2 < NN) rp[base + 2] = pre;
  pre += v2;
  if (base + 3 < NN) rp[base + 3] = pre;
}

__global__ void k_scan2(int* __restrict__ bsum, int nb) {
  if (threadIdx.x == 0 && blockIdx.x == 0) {
    int run = 0;
    for (int b = 0; b < nb; ++b) { int x = bsum[b]; bsum[b] = run; run += x; }
  }
}

__global__ void k_scan3(int* __restrict__ rp, const int* __restrict__ bsum, int* __restrict__ cur) {
  int i = blockIdx.x * 256 + threadIdx.x;
  if (i < NN) {
    int v = rp[i] + bsum[i >> 10];
    rp[i] = v;
    cur[i] = v;
  }
}

// ---------- CSR scatter: bucket edge sources by dst
__global__ void k_scatter(const int* __restrict__ ed, int* __restrict__ cur, int* __restrict__ csr) {
  int e = blockIdx.x * 256 + threadIdx.x;
  if (e < NE) {
    int src = ed[e];
    int dst = ed[NE + e];
    int pos = atomicAdd(&cur[dst], 1);
    csr[pos] = src;
  }
}

// ---------- Y[r][c] = sum_k X[r][k] * W[c][k]   (torch Linear layout W[out][in])
// thread-per-row, 64 accumulators; W loads are wave-uniform -> scalar loads.
// EPI: fuse +bias, relu.
template<int K, bool EPI>
__global__ void __launch_bounds__(256) k_gemm(const float* __restrict__ X, const float* __restrict__ W,
                                              const float* __restrict__ bias, float* __restrict__ Y) {
  int r = blockIdx.x * 256 + threadIdx.x;
  if (r >= NN) return;
  const float4* x4 = reinterpret_cast<const float4*>(X + (size_t)r * K);
  float acc[HID];
  #pragma unroll
  for (int c = 0; c < HID; ++c) acc[c] = 0.f;
  for (int k0 = 0; k0 < K / 4; ++k0) {
    float4 xv = x4[k0];
    #pragma unroll
    for (int c = 0; c < HID; ++c) {
      const float* w = W + c * K + k0 * 4;
      acc[c] = fmaf(xv.x, w[0], fmaf(xv.y, w[1], fmaf(xv.z, w[2], fmaf(xv.w, w[3], acc[c]))));
    }
  }
  float4* y4 = reinterpret_cast<float4*>(Y + (size_t)r * HID);
  #pragma unroll
  for (int c = 0; c < HID / 4; ++c) {
    float4 o;
    o.x = acc[4 * c];     o.y = acc[4 * c + 1];
    o.z = acc[4 * c + 2]; o.w = acc[4 * c + 3];
    if (EPI) {
      o.x = fmaxf(o.x + bias[4 * c],     0.f);
      o.y = fmaxf(o.y + bias[4 * c + 1], 0.f);
      o.z = fmaxf(o.z + bias[4 * c + 2], 0.f);
      o.w = fmaxf(o.w + bias[4 * c + 3], 0.f);
    }
    y4[c] = o;
  }
}

// ---------- aggregation: one wave per dst node, lane = feature; no atomics.
// O[i][:] = sum_{s in N(i)} T[s][:] * dinv[s]*dinv[i]  +  T[i][:]*dinv[i]^2   (+bias, relu if EPI)
template<bool EPI>
__global__ void __launch_bounds__(256) k_agg(const float* __restrict__ T, const int* __restrict__ csr,
                                             const int* __restrict__ rp, const int* __restrict__ edeg,
                                             const float* __restrict__ dinv, const float* __restrict__ bias,
                                             float* __restrict__ O) {
  int node = blockIdx.x * 4 + (threadIdx.x >> 6);
  int lane = threadIdx.x & 63;
  float di = dinv[node];
  float acc = T[(size_t)node * HID + lane] * di * di;  // self-loop
  int start = rp[node];
  int len = edeg[node];
  for (int e = 0; e < len; ++e) {
    int s = csr[start + e];
    acc += T[(size_t)s * HID + lane] * (dinv[s] * di);
  }
  if (EPI) acc = fmaxf(acc + bias[lane], 0.f);
  O[(size_t)node * HID + lane] = acc;
}

extern "C" void kernel_launch(void* const* d_in, const int* in_sizes, int n_in,
                              void* d_out, int out_size, void* d_ws, size_t ws_size,
                              hipStream_t stream) {
  const float* x  = (const float*)d_in[0];
  const int*   ed = (const int*)d_in[1];   // int32 per harness contract
  const float* W1 = (const float*)d_in[2];
  const float* b1 = (const float*)d_in[3];
  const float* W2 = (const float*)d_in[4];
  const float* b2 = (const float*)d_in[5];
  float* out = (float*)d_out;

  char* ws = (char*)d_ws;
  size_t off = 0;
  auto alloc = [&](size_t bytes) {
    char* p = ws + off;
    off = (off + bytes + 255) & ~(size_t)255;
    return p;
  };
  int*   edeg = (int*)alloc((size_t)NN * 4);
  float* dinv = (float*)alloc((size_t)NN * 4);
  int*   rp   = (int*)alloc((size_t)NN * 4);
  int*   cur  = (int*)alloc((size_t)NN * 4);
  int*   bsum = (int*)alloc(4096);
  int*   csr  = (int*)alloc((size_t)NE * 4);
  float* A    = (float*)alloc((size_t)NN * HID * 4);  // single [N,64] scratch; d_out is the other

  // ---- CSR build
  k_zero<<<(NN + 255) / 256, 256, 0, stream>>>(edeg, NN);
  k_deg<<<(NE + 255) / 256, 256, 0, stream>>>(ed, edeg);
  k_dinv<<<(NN + 255) / 256, 256, 0, stream>>>(edeg, dinv);
  int nb = (NN + 1023) / 1024;
  k_scan1<<<nb, 256, 0, stream>>>(edeg, rp, bsum);
  k_scan2<<<1, 1, 0, stream>>>(bsum, nb);
  k_scan3<<<(NN + 255) / 256, 256, 0, stream>>>(rp, bsum, cur);
  k_scatter<<<(NE + 255) / 256, 256, 0, stream>>>(ed, cur, csr);

  // ---- layer 1: t1 = x @ W1^T ; h = relu(Agg(t1) + b1)
  k_gemm<KIN, false><<<(NN + 255) / 256, 256, 0, stream>>>(x, W1, b1, A);
  k_agg<true><<<NN / 4, 256, 0, stream>>>(A, csr, rp, edeg, dinv, b1, out);  // out = h

  // ---- layer 2 (reordered; Agg commutes with right-linear):
  //      g = Agg(h) ; out = relu(g @ W2^T + b2)
  k_agg<false><<<NN / 4, 256, 0, stream>>>(out, csr, rp, edeg, dinv, b2, A); // A = g
  k_gemm<HID, true><<<(NN + 255) / 256, 256, 0, stream>>>(A, W2, b2, out);
}

// Round 3
// 359.548 us; speedup vs baseline: 1.8515x; 1.8515x over previous
//
#include <hip/hip_runtime.h>

static constexpr int NN  = 100000;   // nodes
static constexpr int NE  = 1200000;  // edges
static constexpr int KIN = 256;      // input dim
static constexpr int HID = 64;       // hidden == output dim

// ---------- zero helper (avoid hipMemsetAsync during graph capture)
__global__ void k_zero(int* __restrict__ p, int n) {
  int i = blockIdx.x * 256 + threadIdx.x;
  if (i < n) p[i] = 0;
}

// ---------- degree histogram (in-degree from edges only; +1 self-loop in dinv)
__global__ void k_deg(const int* __restrict__ ed, int* __restrict__ edeg) {
  int e = blockIdx.x * 256 + threadIdx.x;
  if (e < NE) atomicAdd(&edeg[ed[NE + e]], 1);
}

__global__ void k_dinv(const int* __restrict__ edeg, float* __restrict__ dinv) {
  int i = blockIdx.x * 256 + threadIdx.x;
  if (i < NN) dinv[i] = rsqrtf((float)(edeg[i] + 1));
}

// ---------- exclusive scan of edeg -> row_ptr
__global__ void k_scan1(const int* __restrict__ deg, int* __restrict__ rp, int* __restrict__ bsum) {
  __shared__ int sh[256];
  int t = threadIdx.x;
  int base = blockIdx.x * 1024 + t * 4;
  int v0 = 0, v1 = 0, v2 = 0, v3 = 0;
  if (base + 0 < NN) v0 = deg[base + 0];
  if (base + 1 < NN) v1 = deg[base + 1];
  if (base + 2 < NN) v2 = deg[base + 2];
  if (base + 3 < NN) v3 = deg[base + 3];
  int s = v0 + v1 + v2 + v3;
  sh[t] = s;
  __syncthreads();
  #pragma unroll
  for (int off = 1; off < 256; off <<= 1) {
    int x = (t >= off) ? sh[t - off] : 0;
    __syncthreads();
    sh[t] += x;
    __syncthreads();
  }
  int pre = sh[t] - s;
  if (t == 255) bsum[blockIdx.x] = sh[255];
  if (base + 0 < NN) rp[base + 0] = pre;
  pre += v0;
  if (base + 1 < NN) rp[base + 1] = pre;
  pre += v1;
  if (base + 2 < NN) rp[base + 2] = pre;
  pre += v2;
  if (base + 3 < NN) rp[base + 3] = pre;
}

__global__ void k_scan2(int* __restrict__ bsum, int nb) {
  if (threadIdx.x == 0 && blockIdx.x == 0) {
    int run = 0;
    for (int b = 0; b < nb; ++b) { int x = bsum[b]; bsum[b] = run; run += x; }
  }
}

__global__ void k_scan3(int* __restrict__ rp, const int* __restrict__ bsum, int* __restrict__ cur) {
  int i = blockIdx.x * 256 + threadIdx.x;
  if (i < NN) {
    int v = rp[i] + bsum[i >> 10];
    rp[i] = v;
    cur[i] = v;
  }
}

__global__ void k_scatter(const int* __restrict__ ed, int* __restrict__ cur, int* __restrict__ csr) {
  int e = blockIdx.x * 256 + threadIdx.x;
  if (e < NE) {
    int src = ed[e];
    int dst = ed[NE + e];
    int pos = atomicAdd(&cur[dst], 1);
    csr[pos] = src;
  }
}

// ---------- GEMM: Y[r][c] = sum_k X[r][k] * W[c][k]  (torch Linear layout W[out][in])
// Block = 64 rows x 4 waves. lane = row (x from LDS, conflict-free), wave = 16-col slab
// (W via wave-uniform scalar loads). MODE 0: Y = dinv[r]*acc; MODE 1: Y = relu(acc + bias).
template<int K, int MODE>
__global__ void __launch_bounds__(256, 8)
k_gemm(const float* __restrict__ X, const float* __restrict__ W,
       const float* __restrict__ dinv, const float* __restrict__ bias,
       float* __restrict__ Y) {
  constexpr int KT = 64;          // k-tile
  constexpr int NT = K / KT;      // tiles
  constexpr int LS = KT + 4;      // LDS row stride (floats): 68 -> bank-conflict-free b128
  __shared__ float xl[64 * LS];

  const int t = threadIdx.x;
  const int lane = t & 63;
  const int w = __builtin_amdgcn_readfirstlane(t >> 6);  // wave id, forced uniform
  const int rowbase = blockIdx.x * 64;
  const int grow = rowbase + lane;                        // this thread's output row
  const float* Wblk = W + (size_t)(w * 16) * K;           // wave's 16-col slab

  float acc[16];
  #pragma unroll
  for (int c = 0; c < 16; ++c) acc[c] = 0.f;

  const int srow = t >> 4;        // staging: 16 threads per row
  const int scol = (t & 15) * 4;

  for (int kt = 0; kt < NT; ++kt) {
    __syncthreads();
    // stage 64 rows x 64 k-floats, coalesced (16 lanes x float4 per row)
    #pragma unroll
    for (int p = 0; p < 4; ++p) {
      int r = p * 16 + srow;
      int gr = rowbase + r;
      float4 v = make_float4(0.f, 0.f, 0.f, 0.f);
      if (gr < NN) v = *reinterpret_cast<const float4*>(X + (size_t)gr * K + kt * KT + scol);
      *reinterpret_cast<float4*>(&xl[r * LS + scol]) = v;
    }
    __syncthreads();

    #pragma unroll
    for (int k0 = 0; k0 < 16; ++k0) {
      float4 xv = *reinterpret_cast<const float4*>(&xl[lane * LS + k0 * 4]);
      #pragma unroll
      for (int c = 0; c < 16; ++c) {
        float4 wv = *reinterpret_cast<const float4*>(Wblk + c * K + kt * KT + k0 * 4);
        acc[c] = fmaf(xv.x, wv.x, fmaf(xv.y, wv.y, fmaf(xv.z, wv.z, fmaf(xv.w, wv.w, acc[c]))));
      }
    }
  }

  if (grow < NN) {
    float dv = (MODE == 0) ? dinv[grow] : 0.f;
    #pragma unroll
    for (int c4 = 0; c4 < 4; ++c4) {
      float4 o;
      o.x = acc[c4 * 4 + 0]; o.y = acc[c4 * 4 + 1];
      o.z = acc[c4 * 4 + 2]; o.w = acc[c4 * 4 + 3];
      if (MODE == 0) {
        o.x *= dv; o.y *= dv; o.z *= dv; o.w *= dv;
      } else {
        o.x = fmaxf(o.x + bias[w * 16 + c4 * 4 + 0], 0.f);
        o.y = fmaxf(o.y + bias[w * 16 + c4 * 4 + 1], 0.f);
        o.z = fmaxf(o.z + bias[w * 16 + c4 * 4 + 2], 0.f);
        o.w = fmaxf(o.w + bias[w * 16 + c4 * 4 + 3], 0.f);
      }
      *reinterpret_cast<float4*>(Y + (size_t)grow * HID + w * 16 + c4 * 4) = o;
    }
  }
}

// ---------- aggregation over pre-scaled rows T' (= dinv.*T). One wave per node, lane = feature.
// sum = T'[node][lane] + sum_{s in N(node)} T'[s][lane]
// MODE 0 (layer1): O = dinv[node] * relu(dinv[node]*sum + bias[lane])   (outputs h')
// MODE 1 (layer2): O = dinv[node] * sum                                 (outputs g)
template<int MODE>
__global__ void __launch_bounds__(256, 8)
k_agg(const float* __restrict__ T, const int* __restrict__ csr,
      const int* __restrict__ rp, const int* __restrict__ edeg,
      const float* __restrict__ dinv, const float* __restrict__ bias,
      float* __restrict__ O) {
  int node = blockIdx.x * 4 + (threadIdx.x >> 6);
  int lane = threadIdx.x & 63;
  float acc = T[(size_t)node * HID + lane];   // self-loop term (pre-scaled)
  int start = rp[node];
  int len = edeg[node];
  for (int base = 0; base < len; base += 64) {
    int m = min(64, len - base);
    int idx = (lane < m) ? csr[start + base + lane] : 0;   // coalesced index load
    int e = 0;
    for (; e + 4 <= m; e += 4) {
      int s0 = __shfl(idx, e + 0);
      int s1 = __shfl(idx, e + 1);
      int s2 = __shfl(idx, e + 2);
      int s3 = __shfl(idx, e + 3);
      float v0 = T[(size_t)s0 * HID + lane];
      float v1 = T[(size_t)s1 * HID + lane];
      float v2 = T[(size_t)s2 * HID + lane];
      float v3 = T[(size_t)s3 * HID + lane];
      acc += (v0 + v1) + (v2 + v3);
    }
    for (; e < m; ++e) {
      int s = __shfl(idx, e);
      acc += T[(size_t)s * HID + lane];
    }
  }
  float dv = dinv[node];
  if (MODE == 0) acc = dv * fmaxf(fmaf(dv, acc, bias[lane]), 0.f);
  else           acc = dv * acc;
  O[(size_t)node * HID + lane] = acc;
}

extern "C" void kernel_launch(void* const* d_in, const int* in_sizes, int n_in,
                              void* d_out, int out_size, void* d_ws, size_t ws_size,
                              hipStream_t stream) {
  const float* x  = (const float*)d_in[0];
  const int*   ed = (const int*)d_in[1];   // int32 per harness contract
  const float* W1 = (const float*)d_in[2];
  const float* b1 = (const float*)d_in[3];
  const float* W2 = (const float*)d_in[4];
  const float* b2 = (const float*)d_in[5];
  float* out = (float*)d_out;

  char* ws = (char*)d_ws;
  size_t off = 0;
  auto alloc = [&](size_t bytes) {
    char* p = ws + off;
    off = (off + bytes + 255) & ~(size_t)255;
    return p;
  };
  int*   edeg = (int*)alloc((size_t)NN * 4);
  float* dinv = (float*)alloc((size_t)NN * 4);
  int*   rp   = (int*)alloc((size_t)NN * 4);
  int*   cur  = (int*)alloc((size_t)NN * 4);
  int*   bsum = (int*)alloc(4096);
  int*   csr  = (int*)alloc((size_t)NE * 4);
  float* A    = (float*)alloc((size_t)NN * HID * 4);  // t1' then g; d_out doubles as h'

  // ---- CSR build
  k_zero<<<(NN + 255) / 256, 256, 0, stream>>>(edeg, NN);
  k_deg<<<(NE + 255) / 256, 256, 0, stream>>>(ed, edeg);
  k_dinv<<<(NN + 255) / 256, 256, 0, stream>>>(edeg, dinv);
  int nb = (NN + 1023) / 1024;
  k_scan1<<<nb, 256, 0, stream>>>(edeg, rp, bsum);
  k_scan2<<<1, 1, 0, stream>>>(bsum, nb);
  k_scan3<<<(NN + 255) / 256, 256, 0, stream>>>(rp, bsum, cur);
  k_scatter<<<(NE + 255) / 256, 256, 0, stream>>>(ed, cur, csr);

  const int GB = (NN + 63) / 64;  // 1563 gemm blocks

  // layer 1: A = dinv .* (x @ W1^T) ; out(h') = dinv .* relu(dinv.*(Agg A) + b1)
  k_gemm<KIN, 0><<<GB, 256, 0, stream>>>(x, W1, dinv, b1, A);
  k_agg<0><<<NN / 4, 256, 0, stream>>>(A, csr, rp, edeg, dinv, b1, out);

  // layer 2 (agg commutes with right-linear): A(g) = dinv .* (Agg h') ; out = relu(g @ W2^T + b2)
  k_agg<1><<<NN / 4, 256, 0, stream>>>(out, csr, rp, edeg, dinv, b2, A);
  k_gemm<HID, 1><<<GB, 256, 0, stream>>>(A, W2, dinv, b2, out);
}